// Round 4
// baseline (224.778 us; speedup 1.0000x reference)
//
#include <hip/hip_runtime.h>

#define M1 81
#define MSZ 80
#define NEL (M1 * M1)          // 6561
#define NACC 12
#define BIGKC 1.0e30f

// accumulator indices:
// 0 target_num, 1 n_pre, 2 n_next, 3 n_union,
// 4 s_pre, 5 s_next, 6 s_all, 7 s_sim,
// 8 s_acc_pre, 9 s_acc_next, 10 n_mpre, 11 n_mnext

__global__ __launch_bounds__(256) void sst_main(
    const float* __restrict__ input,
    const int* __restrict__ target,
    const int* __restrict__ mask0,
    const int* __restrict__ mask1,
    float* __restrict__ out_idx,   // d_out + 7, [slices*80] floats
    float* __restrict__ part,      // SoA: part[k*slices + slice]
    int slices)
{
    __shared__ float  s_m0[M1];
    __shared__ float2 s_row[M1];      // {lr = log(rsum), 1/rsum}
    __shared__ float2 s_col[M1];      // {kc = log(csum) (1e30 @80), 1/csum}
    __shared__ float  s_cs[4][M1];    // per-wave col csum partials
    __shared__ float  s_cv[4][M1];    // per-wave col argmax value
    __shared__ int    s_ci[4][M1];    // per-wave col argmax row idx
    __shared__ int    s_ct[4][M1];    // per-wave col first-target row (127=none)
    __shared__ float  s_accf[NACC];

    const int tid   = threadIdx.x;
    const int lane  = tid & 63;
    const int w     = tid >> 6;       // wave 0..3
    const int slice = blockIdx.x;
    const size_t base = (size_t)slice * NEL;

    if (tid < NACC) s_accf[tid] = 0.0f;
    if (tid < M1) s_m0[tid] = (float)mask0[slice * M1 + tid];

    // per-lane column constants
    const float m1c1 = (float)mask1[slice * M1 + lane];             // col = lane
    float m1c2 = 0.0f;
    if (lane < 17) m1c2 = (float)mask1[slice * M1 + 64 + lane];     // col = 64+lane
    const float m1n2 = (lane == 16) ? 0.0f : m1c2;                  // next-mask zeroes col 80

    float a[NACC];
#pragma unroll
    for (int k = 0; k < NACC; ++k) a[k] = 0.0f;

    __syncthreads();

    // ================= pass 1: row denominators + column state =================
    float csum1 = 0.0f, csum2 = 0.0f;
    float cmv1 = -1.0f, cmv2 = -1.0f;   // exp(..) > 0 always beats sentinel
    int   cmi1 = 0,     cmi2 = 0;

    for (int r = w; r < M1; r += 4) {
        const float m0f = s_m0[r];
        const size_t rb = base + (size_t)r * M1;
        const float x1 = input[rb + lane];
        float x2 = 0.0f;
        if (lane < 17) x2 = input[rb + 64 + lane];

        if (r < MSZ) {
            // pre-mask == next-mask here (row<80); e covers both uses
            const float e1 = __expf(m0f * m1c1 * x1);
            float e2 = 0.0f;
            if (lane < 17) e2 = __expf(m0f * m1c2 * x2);
            // column state: cols 0..63 (all lanes) and 64..79 (lanes<16)
            csum1 += e1;
            if (e1 > cmv1) { cmv1 = e1; cmi1 = r; }
            if (lane < 16) {
                csum2 += e2;
                if (e2 > cmv2) { cmv2 = e2; cmi2 = r; }
            }
            // row sum over all 81 cols (lane16's e2 is col 80: counts for rsum only)
            float s = e1 + e2;
#pragma unroll
            for (int off = 1; off < 64; off <<= 1) s += __shfl_xor(s, off);
            if (lane == 0) s_row[r] = make_float2(__logf(s), 1.0f / s);
        } else {
            // row 80: pre-mask all-zero -> rsum = 81 exactly; col state uses m0f
            const float e1 = __expf(m0f * m1c1 * x1);
            csum1 += e1;
            if (e1 > cmv1) { cmv1 = e1; cmi1 = MSZ; }
            if (lane < 16) {
                const float e2 = __expf(m0f * m1c2 * x2);
                csum2 += e2;
                if (e2 > cmv2) { cmv2 = e2; cmi2 = MSZ; }
            }
            if (lane == 0) s_row[MSZ] = make_float2(__logf(81.0f), 1.0f / 81.0f);
        }
    }
    // publish per-wave column partials
    s_cs[w][lane] = csum1;
    s_cv[w][lane] = cmv1;
    s_ci[w][lane] = cmi1;
    if (lane < 16) {
        s_cs[w][64 + lane] = csum2;
        s_cv[w][64 + lane] = cmv2;
        s_ci[w][64 + lane] = cmi2;
    }
    __syncthreads();

    // ================= merge column state =================
    if (tid < M1) {
        const int c = tid;
        if (c < MSZ) {
            const float csum = s_cs[0][c] + s_cs[1][c] + s_cs[2][c] + s_cs[3][c];
            float bv = s_cv[0][c]; int bi = s_ci[0][c];
#pragma unroll
            for (int ww = 1; ww < 4; ++ww) {
                const float v = s_cv[ww][c]; const int i = s_ci[ww][c];
                if (v > bv || (v == bv && i < bi)) { bv = v; bi = i; }
            }
            s_ci[0][c] = bi;   // stash argmax row for accuracy_next
            s_col[c] = make_float2(__logf(csum), 1.0f / csum);
        } else {
            s_col[MSZ] = make_float2(BIGKC, 1.0f / 81.0f);  // col 80 sentinel
        }
    }
    __syncthreads();

    // per-lane column constants for pass 2
    const float2 cc1 = s_col[lane];
    const float kc1 = cc1.x, invc1 = cc1.y;
    float kc2 = 0.0f, invc2 = 0.0f;
    if (lane < 17) { const float2 cc2 = s_col[64 + lane]; kc2 = cc2.x; invc2 = cc2.y; }

    // ================= pass 2: all per-element sums + row argmax =================
    int ct1 = 127, ct2 = 127;   // col first-target row (lane-private)

    for (int r = w; r < M1; r += 4) {
        const float m0f = s_m0[r];
        const bool last = (r == MSZ);
        const float m0p = last ? 0.0f : m0f;
        const float2 rw = s_row[r];
        const float lr = rw.x, invr = rw.y;
        const size_t rb = base + (size_t)r * M1;

        const float x1 = input[rb + lane];
        const int   t1 = target[rb + lane];
        float x2 = 0.0f; int t2 = 0;
        if (lane < 17) { x2 = input[rb + 64 + lane]; t2 = target[rb + 64 + lane]; }

        // ---- elem 1: col = lane (always < 80) ----
        const float tf1 = (t1 != 0) ? 1.0f : 0.0f;
        const float mf1 = m0f * m1c1;
        const float z1  = mf1 * x1;
        const float mp1 = m0p * m1c1;
        const float tp1 = tf1 * mp1;
        const float tn1 = tf1 * mf1;
        a[0] += tf1; a[1] += tp1; a[2] += tn1; a[3] += tp1;
        a[4] = fmaf(tp1, lr - z1, a[4]);
        a[5] = fmaf(tn1, kc1 - z1, a[5]);
        const float mlk1 = fminf(lr, kc1);
        a[6] = fmaf(tp1, mlk1 - z1, a[6]);
        const float e1 = __expf(z1);
        a[7] = fmaf(tp1 * e1, fabsf(invc1 - invr), a[7]);
        float bv = z1 - mlk1; int bi = lane;
        const bool tpnz1 = (tp1 != 0.0f);
        if (tn1 != 0.0f && ct1 == 127) ct1 = r;

        // ---- elem 2: col = 64+lane (lanes < 17; lane16 is col 80) ----
        float val2 = -3.402823466e38f;
        bool tpnz2 = false;
        if (lane < 17) {
            const float tf2 = (t2 != 0) ? 1.0f : 0.0f;
            const float mf2 = m0f * m1c2;
            const float z2  = mf2 * x2;
            const float mp2 = m0p * m1c2;
            const float tp2 = tf2 * mp2;
            const float tn2 = tf2 * (m0f * m1n2);
            const float tun2 = (lane == 16) ? 0.0f : tp2;
            a[0] += tf2; a[1] += tp2; a[2] += tn2; a[3] += tun2;
            a[4] = fmaf(tp2, lr - z2, a[4]);
            a[5] = fmaf(tn2, kc2 - z2, a[5]);      // lane16: tn2==0, kc2 finite-big
            const float mlk2 = fminf(lr, kc2);     // lane16: == lr (input_all col80)
            a[6] = fmaf(tp2, mlk2 - z2, a[6]);
            const float e2 = __expf(z2);
            a[7] = fmaf(tun2 * e2, fabsf(invc2 - invr), a[7]);
            val2 = z2 - mlk2;
            tpnz2 = (tp2 != 0.0f);
            if (tn2 != 0.0f && ct2 == 127) ct2 = r;
        }

        // ---- row argmax + first-target + accuracy_pre (rows < 80) ----
        if (!last) {
            if (val2 > bv) { bv = val2; bi = 64 + lane; }   // strict >: col1 wins ties
#pragma unroll
            for (int off = 32; off > 0; off >>= 1) {
                const float v2 = __shfl_down(bv, off);
                const int   i2 = __shfl_down(bi, off);
                if (v2 > bv || (v2 == bv && i2 < bi)) { bv = v2; bi = i2; }
            }
            const unsigned long long b1 = __ballot(tpnz1);
            const unsigned long long b2 = __ballot(tpnz2);
            if (lane == 0) {
                int ti = 0;
                if (b1) ti = __ffsll((long long)b1) - 1;
                else if (b2) ti = 64 + __ffsll((long long)b2) - 1;
                out_idx[(size_t)slice * MSZ + r] = (float)bi;
                a[8]  += (bi == ti) ? m0f : 0.0f;
                a[10] += m0f;
            }
        }
    }

    // publish per-wave col first-target partials
    s_ct[w][lane] = ct1;
    if (lane < 16) s_ct[w][64 + lane] = ct2;
    __syncthreads();

    // ---- accuracy_next (cols < 80) ----
    if (tid < MSZ) {
        const int c = tid;
        int ti = min(min(s_ct[0][c], s_ct[1][c]), min(s_ct[2][c], s_ct[3][c]));
        if (ti == 127) ti = 0;
        const int bi = s_ci[0][c];
        const float m1c = (float)mask1[slice * M1 + c];
        a[9]  += (bi == ti) ? m1c : 0.0f;
        a[11] += m1c;
    }

    // ---- block reduce: wave shuffle -> LDS float atomic -> SoA partials ----
#pragma unroll
    for (int k = 0; k < NACC; ++k) {
        float v = a[k];
        for (int off = 32; off > 0; off >>= 1) v += __shfl_down(v, off);
        if (lane == 0) atomicAdd(&s_accf[k], v);
    }
    __syncthreads();
    if (tid < NACC) part[(size_t)tid * slices + slice] = s_accf[tid];
}

__global__ __launch_bounds__(256) void sst_final(
    const float* __restrict__ part, int slices, float* __restrict__ out)
{
    __shared__ double s_part[4][NACC];
    const int tid = threadIdx.x;
    double l[NACC];
#pragma unroll
    for (int k = 0; k < NACC; ++k) l[k] = 0.0;
    for (int s = tid; s < slices; s += 256) {
#pragma unroll
        for (int k = 0; k < NACC; ++k) l[k] += (double)part[(size_t)k * slices + s];
    }
#pragma unroll
    for (int k = 0; k < NACC; ++k) {
        double v = l[k];
        for (int off = 32; off > 0; off >>= 1) v += __shfl_down(v, off);
        if ((tid & 63) == 0) s_part[tid >> 6][k] = v;
    }
    __syncthreads();
    if (tid == 0) {
        double g[NACC];
#pragma unroll
        for (int k = 0; k < NACC; ++k)
            g[k] = s_part[0][k] + s_part[1][k] + s_part[2][k] + s_part[3][k];
        const double tnum = g[0], npre = g[1], nnext = g[2], nunion = g[3];
        const double spre = g[4], snext = g[5], sall = g[6], ssim = g[7];
        const double accp = g[8], accn = g[9], nmp = g[10], nmn = g[11];
        const double loss_pre  = (npre > 0.0) ? spre / npre : spre;
        const double loss_next = (nnext > 0.0) ? snext / nnext : snext;
        const double loss      = (npre > 0.0 && nnext > 0.0) ? sall / npre : sall;
        const double loss_sim  = (nunion > 0.0) ? ssim / tnum : ssim;
        const double total = (loss_pre + loss_next + loss + loss_sim) * 0.25;
        const double ap = (nmp > 0.0) ? accp / nmp : accp + 1.0;
        const double an = (nmn > 0.0) ? accn / nmn : accn + 1.0;
        out[0] = (float)loss_pre;
        out[1] = (float)loss_next;
        out[2] = (float)loss_sim;
        out[3] = (float)total;
        out[4] = (float)ap;
        out[5] = (float)an;
        out[6] = (float)((ap + an) * 0.5);
    }
}

extern "C" void kernel_launch(void* const* d_in, const int* in_sizes, int n_in,
                              void* d_out, int out_size, void* d_ws, size_t ws_size,
                              hipStream_t stream) {
    const float* input  = (const float*)d_in[0];
    const int*   target = (const int*)d_in[1];
    const int*   mask0  = (const int*)d_in[2];
    const int*   mask1  = (const int*)d_in[3];
    float* out = (float*)d_out;
    float* part = (float*)d_ws;   // NACC * slices floats, SoA

    const int slices = in_sizes[0] / NEL;  // B*C = 2048

    sst_main<<<slices, 256, 0, stream>>>(input, target, mask0, mask1, out + 7, part, slices);
    sst_final<<<1, 256, 0, stream>>>(part, slices, out);
}